// Round 6
// baseline (333.761 us; speedup 1.0000x reference)
//
#include <hip/hip_runtime.h>
#include <stdint.h>

typedef unsigned int uint;
typedef unsigned short ushort;

#define NB_FEATURES 512
#define MB_DIM      10240
#define NB_CLASSES  100
#define BATCH       8192
#define KSEL        32
#define NTHR        256
#define VPT         40    // MB_DIM / NTHR
#define PADOFF      2048u             // byte offset of zero slot (xs[512])
#define PADPAIR     0x08000800u       // two packed pad offsets

static __device__ __forceinline__ uint f2key(float f) {
    uint u = __float_as_uint(f);
    return u ^ (0x80000000u | (uint)((int)u >> 31));  // monotonic
}
static __device__ __forceinline__ float key2f(uint k) {
    uint u = k ^ (0x80000000u | (uint)(((int)~k) >> 31));
    return __uint_as_float(u);
}

// ---------------------------------------------------------------------------
// Kernel A: per w1 row, pack the (>=6, <=8) nonzero columns as 8 x 16-bit
// BYTE offsets (col*4) into one uint4; pad slots = 2048 (zero slot of xs).
// One wave per row; deterministic ascending order via prefix scan.
// ---------------------------------------------------------------------------
__global__ __launch_bounds__(256) void k_extract(const float* __restrict__ w1,
                                                 uint4* __restrict__ idx4) {
    __shared__ ushort scr[4][8];
    const int gw   = (blockIdx.x * 256 + threadIdx.x) >> 6;  // wave id = row
    const int lane = threadIdx.x & 63;
    const int wid  = (threadIdx.x >> 6) & 3;

    const float* row = w1 + (size_t)gw * NB_FEATURES;
    const float4 a = *(const float4*)(row + lane * 8);
    const float4 b = *(const float4*)(row + lane * 8 + 4);
    const float v[8] = {a.x, a.y, a.z, a.w, b.x, b.y, b.z, b.w};
    int cnt = 0;
#pragma unroll
    for (int j = 0; j < 8; ++j) cnt += (v[j] > 0.5f);
    int p = cnt;
#pragma unroll
    for (int off = 1; off < 64; off <<= 1) {
        int n = __shfl_up(p, off, 64);
        if (lane >= off) p += n;
    }
    int slot = p - cnt;  // exclusive prefix (ascending col order)

    if (lane < 8) scr[wid][lane] = (ushort)PADOFF;
    __syncthreads();
#pragma unroll
    for (int j = 0; j < 8; ++j) {
        if (v[j] > 0.5f) {
            if (slot < 8) scr[wid][slot] = (ushort)((lane * 8 + j) * 4);
            slot++;
        }
    }
    __syncthreads();
    if (lane == 0) {
        uint4 q;
        q.x = (uint)scr[wid][0] | ((uint)scr[wid][1] << 16);
        q.y = (uint)scr[wid][2] | ((uint)scr[wid][3] << 16);
        q.z = (uint)scr[wid][4] | ((uint)scr[wid][5] << 16);
        q.w = (uint)scr[wid][6] | ((uint)scr[wid][7] << 16);
        idx4[gw] = q;
    }
}

// ---------------------------------------------------------------------------
// Kernel B: w2t[m][c] = max(w2[c][m], 0)
// ---------------------------------------------------------------------------
__global__ __launch_bounds__(256) void k_w2t(const float* __restrict__ w2,
                                             float* __restrict__ w2t) {
    const int i = blockIdx.x * 256 + threadIdx.x;
    if (i >= NB_CLASSES * MB_DIM) return;
    const int c = i / MB_DIM;
    const int m = i - c * MB_DIM;
    w2t[(size_t)m * NB_CLASSES + c] = fmaxf(w2[i], 0.0f);
}

// ---------------------------------------------------------------------------
// Kernel C: one block (256 threads) per batch row. Plain xs[513] (R1 layout,
// empirically best bank behavior). Gathers via pre-shifted byte offsets:
// addressing = and/lshr only; xs LDS base folds into ds_read imm offset.
// ---------------------------------------------------------------------------
#define LD(o) (*(const float*)((const char*)xs + (o)))

template <bool USE_W2T>
__global__ __launch_bounds__(NTHR, 8) void k_main(
    const float* __restrict__ x, const uint4* __restrict__ idx4,
    const float* __restrict__ w2t, const float* __restrict__ w2,
    const float* __restrict__ b2, float* __restrict__ out)
{
    __shared__ float xs[513];        // xs[512] = 0 (pad target), FIRST in LDS
    __shared__ float cand[512];
    __shared__ uint  s_wsum[4];
    __shared__ float s_piv[4];
    __shared__ float s_thf;
    __shared__ uint  s_cnt1;
    __shared__ uint  s_pref;
    __shared__ int   s_k;
    __shared__ uint  list_m[64];
    __shared__ float list_v[64];

    const int tid  = threadIdx.x;
    const int lane = tid & 63;
    const int wid  = tid >> 6;           // 0..3
    const int brow = blockIdx.x;

    // 1. stage x row
    {
        xs[tid]       = x[(size_t)brow * NB_FEATURES + tid];
        xs[tid + 256] = x[(size_t)brow * NB_FEATURES + tid + 256];
        if (tid == 0) xs[512] = 0.0f;
        if (tid < 64) { list_m[tid] = 0u; list_v[tid] = 0.0f; }
    }
    __syncthreads();

    // 2. gather: 6 reads/m + rare execz-skipped extra pair (tie-overflow rows)
    float vals[VPT];
    const uint4* ip = idx4 + tid;
#pragma unroll 1
    for (int ii = 0; ii < VPT / 2; ++ii) {
#pragma unroll
        for (int j = 0; j < 2; ++j) {
            const int i = ii * 2 + j;
            const uint4 q = ip[(size_t)i << 8];
            const float s0 = LD(q.x & 0xFFFFu) + LD(q.x >> 16);
            const float s1 = LD(q.y & 0xFFFFu) + LD(q.y >> 16);
            const float s2 = LD(q.z & 0xFFFFu) + LD(q.z >> 16);
            float s = (s0 + s1) + s2;
            if (q.w != PADPAIR) {
                s += LD(q.w & 0xFFFFu) + LD(q.w >> 16);
            }
            vals[i] = s;
        }
    }

    // 3. pivot: thread max -> wave bitonic sort(64) -> wave rank-31 ->
    //    pivot = max over 4 waves (provably <= true 32nd-largest)
    {
        float v = vals[0];
#pragma unroll
        for (int i = 1; i < VPT; ++i) v = fmaxf(v, vals[i]);
#pragma unroll
        for (int k = 2; k <= 64; k <<= 1) {
#pragma unroll
            for (int j = k >> 1; j > 0; j >>= 1) {
                const float pr = __shfl_xor(v, j, 64);
                const bool lower = (lane & j) == 0;
                const bool asc   = (lane & k) == 0;
                const float mn = fminf(v, pr), mx = fmaxf(v, pr);
                v = (lower == asc) ? mx : mn;  // descending
            }
        }
        if (lane == 31) s_piv[wid] = v;
    }
    __syncthreads();
    const float pivot = fmaxf(fmaxf(s_piv[0], s_piv[1]), fmaxf(s_piv[2], s_piv[3]));

    // 4. compact candidates (>= pivot) into LDS
    int myc = 0;
#pragma unroll
    for (int i = 0; i < VPT; ++i) myc += (vals[i] >= pivot) ? 1 : 0;
    int p = myc;
#pragma unroll
    for (int off = 1; off < 64; off <<= 1) {
        int n = __shfl_up(p, off, 64);
        if (lane >= off) p += n;
    }
    if (lane == 63) s_wsum[wid] = (uint)p;
    __syncthreads();
    int base = p - myc;
    for (int w = 0; w < wid; ++w) base += (int)s_wsum[w];
    const int ctot = (int)(s_wsum[0] + s_wsum[1] + s_wsum[2] + s_wsum[3]);
    {
        int slot = base;
#pragma unroll
        for (int i = 0; i < VPT; ++i) {
            if (vals[i] >= pivot) {
                if (slot < 512) cand[slot] = vals[i];
                slot++;
            }
        }
    }
    __syncthreads();

    // 5. exact 32nd-largest (ties -> same float threshold as reference);
    //    strided so 256 threads cover up to 512 candidates.
    if (ctot <= 512) {
        for (int pos = tid; pos < ctot; pos += NTHR) {
            const float u = cand[pos];
            int rank = 0;
            for (int j = 0; j < ctot; ++j) {
                const float vv = cand[j];
                rank += ((vv > u) || (vv == u && j < pos)) ? 1 : 0;
            }
            if (rank == KSEL - 1) s_thf = u;
        }
    } else {  // pathological tie flood: exact radix on monotonic keys
        if (tid == 0) { s_pref = 0u; s_k = KSEL; }
        __syncthreads();
        for (int bit = 31; bit >= 0; --bit) {
            const uint bmask = 1u << bit;
            const uint dmask = (bit == 31) ? 0u : (0xFFFFFFFFu << (bit + 1));
            const uint pref = s_pref;
            int mc = 0;
#pragma unroll
            for (int i = 0; i < VPT; ++i) {
                const uint k = f2key(vals[i]);
                mc += (((k & dmask) == pref) && (k & bmask)) ? 1 : 0;
            }
            if (tid == 0) s_cnt1 = 0;
            __syncthreads();
            if (mc) atomicAdd(&s_cnt1, (uint)mc);
            __syncthreads();
            if (tid == 0) {
                if ((int)s_cnt1 >= s_k) s_pref = pref | bmask;
                else s_k -= (int)s_cnt1;
            }
            __syncthreads();
        }
        if (tid == 0) s_thf = key2f(s_pref);
    }
    __syncthreads();
    const float thf = s_thf;

    // 6. final compaction of kept entries (>= thf), zero-padded to 64
    int kc = 0;
#pragma unroll
    for (int i = 0; i < VPT; ++i) kc += (vals[i] >= thf) ? 1 : 0;
    int p2 = kc;
#pragma unroll
    for (int off = 1; off < 64; off <<= 1) {
        int n = __shfl_up(p2, off, 64);
        if (lane >= off) p2 += n;
    }
    if (lane == 63) s_wsum[wid] = (uint)p2;
    __syncthreads();
    int kbase = p2 - kc;
    for (int w = 0; w < wid; ++w) kbase += (int)s_wsum[w];
    {
        int slot = kbase;
#pragma unroll
        for (int i = 0; i < VPT; ++i) {
            if (vals[i] >= thf) {
                if (slot < 64) {
                    list_m[slot] = (uint)(tid + (i << 8));
                    list_v[slot] = vals[i];
                }
                slot++;
            }
        }
    }
    __syncthreads();

    // 7. out[b][c] = b2[c] + sum_j v_j * w2t[m_j][c]  (fully unrolled, padded)
    if (tid < NB_CLASSES) {
        float a0 = b2[tid], a1 = 0.0f;
#pragma unroll
        for (int j = 0; j < 64; j += 2) {
            const uint m0 = list_m[j], m1 = list_m[j + 1];
            float w0, w1;
            if (USE_W2T) {
                w0 = w2t[(size_t)m0 * NB_CLASSES + tid];
                w1 = w2t[(size_t)m1 * NB_CLASSES + tid];
            } else {
                w0 = fmaxf(w2[(size_t)tid * MB_DIM + m0], 0.0f);
                w1 = fmaxf(w2[(size_t)tid * MB_DIM + m1], 0.0f);
            }
            a0 = fmaf(list_v[j],     w0, a0);
            a1 = fmaf(list_v[j + 1], w1, a1);
        }
        out[(size_t)brow * NB_CLASSES + tid] = a0 + a1;
    }
}

// ---------------------------------------------------------------------------
extern "C" void kernel_launch(void* const* d_in, const int* in_sizes, int n_in,
                              void* d_out, int out_size, void* d_ws, size_t ws_size,
                              hipStream_t stream) {
    const float* x  = (const float*)d_in[0];
    const float* w1 = (const float*)d_in[1];
    const float* w2 = (const float*)d_in[2];
    const float* b2 = (const float*)d_in[3];
    float* out = (float*)d_out;

    uint4* idx4 = (uint4*)d_ws;                            // 163840 B
    const size_t W2T_OFF = 163840;
    float* w2t = (float*)((char*)d_ws + W2T_OFF);
    const bool use_w2t =
        ws_size >= W2T_OFF + (size_t)MB_DIM * NB_CLASSES * sizeof(float);

    k_extract<<<(MB_DIM * 64) / 256, 256, 0, stream>>>(w1, idx4);
    if (use_w2t) {
        k_w2t<<<(MB_DIM * NB_CLASSES + 255) / 256, 256, 0, stream>>>(w2, w2t);
        k_main<true><<<BATCH, NTHR, 0, stream>>>(x, idx4, w2t, w2, b2, out);
    } else {
        k_main<false><<<BATCH, NTHR, 0, stream>>>(x, idx4, nullptr, w2, b2, out);
    }
}

// Round 7
// 237.832 us; speedup vs baseline: 1.4033x; 1.4033x over previous
//
#include <hip/hip_runtime.h>
#include <stdint.h>

typedef unsigned int uint;
typedef unsigned short ushort;

#define NB_FEATURES 512
#define MB_DIM      10240
#define NB_CLASSES  100
#define BATCH       8192
#define KSEL        32
#define NTHR        256
#define VPH         20          // values per thread per phase
#define NPH         2
#define PHSTRIDE    5120        // m-stride between phases
#define POOLCAP     1024
#define PADOFF      2048u       // byte offset of zero slot (xs[512])
#define PADPAIR     0x08000800u

static __device__ __forceinline__ uint f2key(float f) {
    uint u = __float_as_uint(f);
    return u ^ (0x80000000u | (uint)((int)u >> 31));  // monotonic
}
static __device__ __forceinline__ float key2f(uint k) {
    uint u = k ^ (0x80000000u | (uint)(((int)~k) >> 31));
    return __uint_as_float(u);
}

// ---------------------------------------------------------------------------
// Kernel A: per w1 row, pack the (>=6, <=8) nonzero columns as 8 x 16-bit
// BYTE offsets (col*4) into one uint4; pad slots = 2048 (zero slot of xs).
// (Validated correct in round 6.)
// ---------------------------------------------------------------------------
__global__ __launch_bounds__(256) void k_extract(const float* __restrict__ w1,
                                                 uint4* __restrict__ idx4) {
    __shared__ ushort scr[4][8];
    const int gw   = (blockIdx.x * 256 + threadIdx.x) >> 6;  // wave id = row
    const int lane = threadIdx.x & 63;
    const int wid  = (threadIdx.x >> 6) & 3;

    const float* row = w1 + (size_t)gw * NB_FEATURES;
    const float4 a = *(const float4*)(row + lane * 8);
    const float4 b = *(const float4*)(row + lane * 8 + 4);
    const float v[8] = {a.x, a.y, a.z, a.w, b.x, b.y, b.z, b.w};
    int cnt = 0;
#pragma unroll
    for (int j = 0; j < 8; ++j) cnt += (v[j] > 0.5f);
    int p = cnt;
#pragma unroll
    for (int off = 1; off < 64; off <<= 1) {
        int n = __shfl_up(p, off, 64);
        if (lane >= off) p += n;
    }
    int slot = p - cnt;  // exclusive prefix (ascending col order)

    if (lane < 8) scr[wid][lane] = (ushort)PADOFF;
    __syncthreads();
#pragma unroll
    for (int j = 0; j < 8; ++j) {
        if (v[j] > 0.5f) {
            if (slot < 8) scr[wid][slot] = (ushort)((lane * 8 + j) * 4);
            slot++;
        }
    }
    __syncthreads();
    if (lane == 0) {
        uint4 q;
        q.x = (uint)scr[wid][0] | ((uint)scr[wid][1] << 16);
        q.y = (uint)scr[wid][2] | ((uint)scr[wid][3] << 16);
        q.z = (uint)scr[wid][4] | ((uint)scr[wid][5] << 16);
        q.w = (uint)scr[wid][6] | ((uint)scr[wid][7] << 16);
        idx4[gw] = q;
    }
}

// ---------------------------------------------------------------------------
// Kernel B: w2t[m][c] = max(w2[c][m], 0)
// ---------------------------------------------------------------------------
__global__ __launch_bounds__(256) void k_w2t(const float* __restrict__ w2,
                                             float* __restrict__ w2t) {
    const int i = blockIdx.x * 256 + threadIdx.x;
    if (i >= NB_CLASSES * MB_DIM) return;
    const int c = i / MB_DIM;
    const int m = i - c * MB_DIM;
    w2t[(size_t)m * NB_CLASSES + c] = fmaxf(w2[i], 0.0f);
}

// ---------------------------------------------------------------------------
// Kernel C: one block (256 threads) per batch row, TWO phases of 20 values
// per thread -> live register state halved vs R1. Per-phase safe pivot via
// wave bitonic; candidates pooled in LDS as (val, m); exact rank-31 on pool.
// ---------------------------------------------------------------------------
#define LD(o) (*(const float*)((const char*)xs + (o)))

template <bool USE_W2T>
__global__ __launch_bounds__(NTHR) void k_main(
    const float* __restrict__ x, const uint4* __restrict__ idx4,
    const float* __restrict__ w2t, const float* __restrict__ w2,
    const float* __restrict__ b2, float* __restrict__ out)
{
    __shared__ float  xs[513];        // xs[512] = 0 (pad target)
    __shared__ float  poolv[POOLCAP];
    __shared__ ushort poolm[POOLCAP];
    __shared__ uint   s_wsum[4];
    __shared__ float  s_piv[4];
    __shared__ uint   s_pbase;
    __shared__ float  s_thf;
    __shared__ uint   s_cnt1;
    __shared__ uint   s_pref;
    __shared__ int    s_k;
    __shared__ uint   list_m[64];
    __shared__ float  list_v[64];

    const int tid  = threadIdx.x;
    const int lane = tid & 63;
    const int wid  = tid >> 6;           // 0..3
    const int brow = blockIdx.x;

    xs[tid]       = x[(size_t)brow * NB_FEATURES + tid];
    xs[tid + 256] = x[(size_t)brow * NB_FEATURES + tid + 256];
    if (tid == 0) { xs[512] = 0.0f; s_pbase = 0u; }
    if (tid < 64) { list_m[tid] = 0u; list_v[tid] = 0.0f; }
    __syncthreads();

    // recompute h for (ph, i) -- used only by the cold fallback path
    auto h_of = [&](int ph, int i) -> float {
        const uint4 q = idx4[ph * PHSTRIDE + (i << 8) + tid];
        float s = LD(q.x & 0xFFFFu) + LD(q.x >> 16)
                + LD(q.y & 0xFFFFu) + LD(q.y >> 16)
                + LD(q.z & 0xFFFFu) + LD(q.z >> 16);
        if (q.w != PADPAIR) s += LD(q.w & 0xFFFFu) + LD(q.w >> 16);
        return s;
    };

    // gather + pivot + compact, two phases; pool accumulates in s_pbase
    auto build_pool = [&](bool use_bitonic, float fpiv) {
        float runpiv = fpiv;
        for (int ph = 0; ph < NPH; ++ph) {
            float vals[VPH];
            const uint4* ip = idx4 + ph * PHSTRIDE + tid;
#pragma unroll
            for (int i = 0; i < VPH; ++i) {
                const uint4 q = ip[i << 8];
                float s = LD(q.x & 0xFFFFu) + LD(q.x >> 16)
                        + LD(q.y & 0xFFFFu) + LD(q.y >> 16)
                        + LD(q.z & 0xFFFFu) + LD(q.z >> 16);
                if (q.w != PADPAIR) s += LD(q.w & 0xFFFFu) + LD(q.w >> 16);
                vals[i] = s;
            }
            float pivot;
            if (use_bitonic) {
                float v = vals[0];
#pragma unroll
                for (int i = 1; i < VPH; ++i) v = fmaxf(v, vals[i]);
#pragma unroll
                for (int k = 2; k <= 64; k <<= 1) {
#pragma unroll
                    for (int j = k >> 1; j > 0; j >>= 1) {
                        const float pr = __shfl_xor(v, j, 64);
                        const bool lower = (lane & j) == 0;
                        const bool asc   = (lane & k) == 0;
                        const float mn = fminf(v, pr), mx = fmaxf(v, pr);
                        v = (lower == asc) ? mx : mn;  // descending
                    }
                }
                if (lane == 31) s_piv[wid] = v;
                __syncthreads();
                pivot = fmaxf(fmaxf(s_piv[0], s_piv[1]),
                              fmaxf(s_piv[2], s_piv[3]));
                pivot = fmaxf(pivot, runpiv);
                runpiv = pivot;
            } else {
                pivot = fpiv;
                __syncthreads();
            }
            // count + prefix scan + compact into pool
            int myc = 0;
#pragma unroll
            for (int i = 0; i < VPH; ++i) myc += (vals[i] >= pivot) ? 1 : 0;
            int p = myc;
#pragma unroll
            for (int off = 1; off < 64; off <<= 1) {
                int n = __shfl_up(p, off, 64);
                if (lane >= off) p += n;
            }
            if (lane == 63) s_wsum[wid] = (uint)p;
            __syncthreads();
            int slot = (int)s_pbase + p - myc;
            for (int w = 0; w < wid; ++w) slot += (int)s_wsum[w];
#pragma unroll
            for (int i = 0; i < VPH; ++i) {
                if (vals[i] >= pivot) {
                    if (slot < POOLCAP) {
                        poolv[slot] = vals[i];
                        poolm[slot] = (ushort)(ph * PHSTRIDE + (i << 8) + tid);
                    }
                    slot++;
                }
            }
            __syncthreads();
            if (tid == 0)
                s_pbase += s_wsum[0] + s_wsum[1] + s_wsum[2] + s_wsum[3];
            __syncthreads();
        }
    };

    build_pool(true, -3.4e38f);
    int ctot = (int)s_pbase;

    if (ctot <= POOLCAP) {
        // exact 32nd-largest on the pool (ties: same float th as reference)
        for (int pos = tid; pos < ctot; pos += NTHR) {
            const float u = poolv[pos];
            int rank = 0;
            for (int j = 0; j < ctot; ++j) {
                const float vv = poolv[j];
                rank += ((vv > u) || (vv == u && j < pos)) ? 1 : 0;
            }
            if (rank == KSEL - 1) s_thf = u;
        }
        __syncthreads();
    } else {
        // cold exact fallback: radix over recomputed keys, then rebuild pool
        if (tid == 0) { s_pref = 0u; s_k = KSEL; }
        __syncthreads();
        for (int bit = 31; bit >= 0; --bit) {
            const uint bmask = 1u << bit;
            const uint dmask = (bit == 31) ? 0u : (0xFFFFFFFFu << (bit + 1));
            const uint pref = s_pref;
            int mc = 0;
#pragma unroll 1
            for (int ph = 0; ph < NPH; ++ph) {
#pragma unroll 1
                for (int i = 0; i < VPH; ++i) {
                    const uint k = f2key(h_of(ph, i));
                    mc += (((k & dmask) == pref) && (k & bmask)) ? 1 : 0;
                }
            }
            if (tid == 0) s_cnt1 = 0;
            __syncthreads();
            if (mc) atomicAdd(&s_cnt1, (uint)mc);
            __syncthreads();
            if (tid == 0) {
                if ((int)s_cnt1 >= s_k) s_pref = pref | bmask;
                else s_k -= (int)s_cnt1;
            }
            __syncthreads();
        }
        if (tid == 0) { s_thf = key2f(s_pref); s_pbase = 0u; }
        __syncthreads();
        build_pool(false, s_thf);     // pool := exactly the kept entries
        ctot = (int)s_pbase;
    }
    const float thf = s_thf;

    // compact kept entries (>= thf) from pool into 64-padded list
    int myk = 0;
    for (int pos = tid; pos < ctot; pos += NTHR)
        myk += (poolv[pos] >= thf) ? 1 : 0;
    int p2 = myk;
#pragma unroll
    for (int off = 1; off < 64; off <<= 1) {
        int n = __shfl_up(p2, off, 64);
        if (lane >= off) p2 += n;
    }
    if (lane == 63) s_wsum[wid] = (uint)p2;
    __syncthreads();
    int slot = p2 - myk;
    for (int w = 0; w < wid; ++w) slot += (int)s_wsum[w];
    for (int pos = tid; pos < ctot; pos += NTHR) {
        if (poolv[pos] >= thf) {
            if (slot < 64) {
                list_m[slot] = (uint)poolm[pos];
                list_v[slot] = poolv[pos];
            }
            slot++;
        }
    }
    __syncthreads();

    // out[b][c] = b2[c] + sum_j v_j * w2t[m_j][c]  (fully unrolled, padded)
    if (tid < NB_CLASSES) {
        float a0 = b2[tid], a1 = 0.0f;
#pragma unroll
        for (int j = 0; j < 64; j += 2) {
            const uint m0 = list_m[j], m1 = list_m[j + 1];
            float w0, w1;
            if (USE_W2T) {
                w0 = w2t[(size_t)m0 * NB_CLASSES + tid];
                w1 = w2t[(size_t)m1 * NB_CLASSES + tid];
            } else {
                w0 = fmaxf(w2[(size_t)tid * MB_DIM + m0], 0.0f);
                w1 = fmaxf(w2[(size_t)tid * MB_DIM + m1], 0.0f);
            }
            a0 = fmaf(list_v[j],     w0, a0);
            a1 = fmaf(list_v[j + 1], w1, a1);
        }
        out[(size_t)brow * NB_CLASSES + tid] = a0 + a1;
    }
}

// ---------------------------------------------------------------------------
extern "C" void kernel_launch(void* const* d_in, const int* in_sizes, int n_in,
                              void* d_out, int out_size, void* d_ws, size_t ws_size,
                              hipStream_t stream) {
    const float* x  = (const float*)d_in[0];
    const float* w1 = (const float*)d_in[1];
    const float* w2 = (const float*)d_in[2];
    const float* b2 = (const float*)d_in[3];
    float* out = (float*)d_out;

    uint4* idx4 = (uint4*)d_ws;                            // 163840 B
    const size_t W2T_OFF = 163840;
    float* w2t = (float*)((char*)d_ws + W2T_OFF);
    const bool use_w2t =
        ws_size >= W2T_OFF + (size_t)MB_DIM * NB_CLASSES * sizeof(float);

    k_extract<<<(MB_DIM * 64) / 256, 256, 0, stream>>>(w1, idx4);
    if (use_w2t) {
        k_w2t<<<(MB_DIM * NB_CLASSES + 255) / 256, 256, 0, stream>>>(w2, w2t);
        k_main<true><<<BATCH, NTHR, 0, stream>>>(x, idx4, w2t, w2, b2, out);
    } else {
        k_main<false><<<BATCH, NTHR, 0, stream>>>(x, idx4, nullptr, w2, b2, out);
    }
}

// Round 8
// 190.176 us; speedup vs baseline: 1.7550x; 1.2506x over previous
//
#include <hip/hip_runtime.h>
#include <stdint.h>

typedef unsigned int uint;
typedef unsigned short ushort;

#define NB_FEATURES 512
#define MB_DIM      10240
#define NB_CLASSES  100
#define BATCH       8192
#define KSEL        32
#define NTHR        256
#define VPT         40            // m per thread (per pair-block)
#define PADOFF      4096u         // byte offset of zero slot (xs2[512], float2)
#define PADPAIR     0x10001000u   // two packed pad offsets

static __device__ __forceinline__ uint f2key(float f) {
    uint u = __float_as_uint(f);
    return u ^ (0x80000000u | (uint)((int)u >> 31));  // monotonic
}
static __device__ __forceinline__ float key2f(uint k) {
    uint u = k ^ (0x80000000u | (uint)(((int)~k) >> 31));
    return __uint_as_float(u);
}

// ---------------------------------------------------------------------------
// Kernel A: per w1 row, pack the (>=6, <=8) nonzero columns as 8 x 16-bit
// BYTE offsets (col*8, float2 stride) into one uint4; pad = 4096 (zero slot).
// ---------------------------------------------------------------------------
__global__ __launch_bounds__(256) void k_extract(const float* __restrict__ w1,
                                                 uint4* __restrict__ idx4) {
    __shared__ ushort scr[4][8];
    const int gw   = (blockIdx.x * 256 + threadIdx.x) >> 6;  // wave id = row
    const int lane = threadIdx.x & 63;
    const int wid  = (threadIdx.x >> 6) & 3;

    const float* row = w1 + (size_t)gw * NB_FEATURES;
    const float4 a = *(const float4*)(row + lane * 8);
    const float4 b = *(const float4*)(row + lane * 8 + 4);
    const float v[8] = {a.x, a.y, a.z, a.w, b.x, b.y, b.z, b.w};
    int cnt = 0;
#pragma unroll
    for (int j = 0; j < 8; ++j) cnt += (v[j] > 0.5f);
    int p = cnt;
#pragma unroll
    for (int off = 1; off < 64; off <<= 1) {
        int n = __shfl_up(p, off, 64);
        if (lane >= off) p += n;
    }
    int slot = p - cnt;  // exclusive prefix (ascending col order)

    if (lane < 8) scr[wid][lane] = (ushort)PADOFF;
    __syncthreads();
#pragma unroll
    for (int j = 0; j < 8; ++j) {
        if (v[j] > 0.5f) {
            if (slot < 8) scr[wid][slot] = (ushort)((lane * 8 + j) * 8);
            slot++;
        }
    }
    __syncthreads();
    if (lane == 0) {
        uint4 q;
        q.x = (uint)scr[wid][0] | ((uint)scr[wid][1] << 16);
        q.y = (uint)scr[wid][2] | ((uint)scr[wid][3] << 16);
        q.z = (uint)scr[wid][4] | ((uint)scr[wid][5] << 16);
        q.w = (uint)scr[wid][6] | ((uint)scr[wid][7] << 16);
        idx4[gw] = q;
    }
}

// ---------------------------------------------------------------------------
// Kernel B: w2t[m][c] = max(w2[c][m], 0)
// ---------------------------------------------------------------------------
__global__ __launch_bounds__(256) void k_w2t(const float* __restrict__ w2,
                                             float* __restrict__ w2t) {
    const int i = blockIdx.x * 256 + threadIdx.x;
    if (i >= NB_CLASSES * MB_DIM) return;
    const int c = i / MB_DIM;
    const int m = i - c * MB_DIM;
    w2t[(size_t)m * NB_CLASSES + c] = fmaxf(w2[i], 0.0f);
}

// ---------------------------------------------------------------------------
// Kernel C: one block (256 threads) per TWO batch rows. xs2[col] = float2 of
// both rows; one ds_read_b64 per (m, entry) feeds both rows. R1-lean
// selection run per row on register-resident vals.
// ---------------------------------------------------------------------------
#define LD2(o) (*(const float2*)((const char*)xs2 + (o)))

template <bool USE_W2T>
__global__ __launch_bounds__(NTHR) void k_main(
    const float* __restrict__ x, const uint4* __restrict__ idx4,
    const float* __restrict__ w2t, const float* __restrict__ w2,
    const float* __restrict__ b2, float* __restrict__ out)
{
    __shared__ float2 xs2[513];      // xs2[512] = 0 (pad target)
    __shared__ float  cand[512];
    __shared__ uint   s_wsum[4];
    __shared__ float  s_piv[4];
    __shared__ float  s_thf;
    __shared__ uint   s_cnt1;
    __shared__ uint   s_pref;
    __shared__ int    s_k;
    __shared__ uint   list_m[2][64];
    __shared__ float  list_v[2][64];

    const int tid  = threadIdx.x;
    const int lane = tid & 63;
    const int wid  = tid >> 6;           // 0..3
    const int brow = blockIdx.x * 2;

    // 1. stage both rows as float2
    {
        float2 v0, v1;
        v0.x = x[(size_t)brow * NB_FEATURES + tid];
        v0.y = x[(size_t)(brow + 1) * NB_FEATURES + tid];
        v1.x = x[(size_t)brow * NB_FEATURES + tid + 256];
        v1.y = x[(size_t)(brow + 1) * NB_FEATURES + tid + 256];
        xs2[tid]       = v0;
        xs2[tid + 256] = v1;
        if (tid == 0) { float2 z; z.x = 0.0f; z.y = 0.0f; xs2[512] = z; }
        if (tid < 64) {
            list_m[0][tid] = 0u; list_v[0][tid] = 0.0f;
            list_m[1][tid] = 0u; list_v[1][tid] = 0.0f;
        }
    }
    __syncthreads();

    // 2. gather: 6 b64 reads per m (+ rare execz-skipped pair), both rows
    float vA[VPT], vB[VPT];
    const uint4* ip = idx4 + tid;
#pragma unroll
    for (int i = 0; i < VPT; ++i) {
        const uint4 q = ip[i << 8];
        const float2 g0 = LD2(q.x & 0xFFFFu);
        const float2 g1 = LD2(q.x >> 16);
        const float2 g2 = LD2(q.y & 0xFFFFu);
        const float2 g3 = LD2(q.y >> 16);
        const float2 g4 = LD2(q.z & 0xFFFFu);
        const float2 g5 = LD2(q.z >> 16);
        float sx = ((g0.x + g1.x) + (g2.x + g3.x)) + (g4.x + g5.x);
        float sy = ((g0.y + g1.y) + (g2.y + g3.y)) + (g4.y + g5.y);
        if (q.w != PADPAIR) {    // rare tie-overflow rows (>6 nonzeros)
            const float2 e0 = LD2(q.w & 0xFFFFu);
            const float2 e1 = LD2(q.w >> 16);
            sx += e0.x + e1.x;
            sy += e0.y + e1.y;
        }
        vA[i] = sx;
        vB[i] = sy;
    }

    // 3-6. per-row selection on register-resident vals (R1-lean)
    auto select_row = [&](float (&vals)[VPT], int r) {
        // 3. pivot: thread max -> wave bitonic sort(64) -> wave rank-31 ->
        //    pivot = max over 4 waves (provably <= true 32nd-largest)
        {
            float v = vals[0];
#pragma unroll
            for (int i = 1; i < VPT; ++i) v = fmaxf(v, vals[i]);
#pragma unroll
            for (int k = 2; k <= 64; k <<= 1) {
#pragma unroll
                for (int j = k >> 1; j > 0; j >>= 1) {
                    const float pr = __shfl_xor(v, j, 64);
                    const bool lower = (lane & j) == 0;
                    const bool asc   = (lane & k) == 0;
                    const float mn = fminf(v, pr), mx = fmaxf(v, pr);
                    v = (lower == asc) ? mx : mn;  // descending
                }
            }
            if (lane == 31) s_piv[wid] = v;
        }
        __syncthreads();
        const float pivot = fmaxf(fmaxf(s_piv[0], s_piv[1]),
                                  fmaxf(s_piv[2], s_piv[3]));

        // 4. compact candidate values (>= pivot) into LDS
        int myc = 0;
#pragma unroll
        for (int i = 0; i < VPT; ++i) myc += (vals[i] >= pivot) ? 1 : 0;
        int p = myc;
#pragma unroll
        for (int off = 1; off < 64; off <<= 1) {
            int n = __shfl_up(p, off, 64);
            if (lane >= off) p += n;
        }
        if (lane == 63) s_wsum[wid] = (uint)p;
        __syncthreads();
        int base = p - myc;
        for (int w = 0; w < wid; ++w) base += (int)s_wsum[w];
        const int ctot = (int)(s_wsum[0] + s_wsum[1] + s_wsum[2] + s_wsum[3]);
        {
            int slot = base;
#pragma unroll
            for (int i = 0; i < VPT; ++i) {
                if (vals[i] >= pivot) {
                    if (slot < 512) cand[slot] = vals[i];
                    slot++;
                }
            }
        }
        __syncthreads();

        // 5. exact 32nd-largest (ties -> same float threshold as reference)
        if (ctot <= 512) {
            for (int pos = tid; pos < ctot; pos += NTHR) {
                const float u = cand[pos];
                int rank = 0;
                for (int j = 0; j < ctot; ++j) {
                    const float vv = cand[j];
                    rank += ((vv > u) || (vv == u && j < pos)) ? 1 : 0;
                }
                if (rank == KSEL - 1) s_thf = u;
            }
        } else {  // pathological tie flood: exact radix on register vals
            if (tid == 0) { s_pref = 0u; s_k = KSEL; }
            __syncthreads();
            for (int bit = 31; bit >= 0; --bit) {
                const uint bmask = 1u << bit;
                const uint dmask = (bit == 31) ? 0u : (0xFFFFFFFFu << (bit + 1));
                const uint pref = s_pref;
                int mc = 0;
#pragma unroll
                for (int i = 0; i < VPT; ++i) {
                    const uint k = f2key(vals[i]);
                    mc += (((k & dmask) == pref) && (k & bmask)) ? 1 : 0;
                }
                if (tid == 0) s_cnt1 = 0;
                __syncthreads();
                if (mc) atomicAdd(&s_cnt1, (uint)mc);
                __syncthreads();
                if (tid == 0) {
                    if ((int)s_cnt1 >= s_k) s_pref = pref | bmask;
                    else s_k -= (int)s_cnt1;
                }
                __syncthreads();
            }
            if (tid == 0) s_thf = key2f(s_pref);
        }
        __syncthreads();
        const float thf = s_thf;

        // 6. final compaction (>= thf) from registers into list[r]
        int kc = 0;
#pragma unroll
        for (int i = 0; i < VPT; ++i) kc += (vals[i] >= thf) ? 1 : 0;
        int p2 = kc;
#pragma unroll
        for (int off = 1; off < 64; off <<= 1) {
            int n = __shfl_up(p2, off, 64);
            if (lane >= off) p2 += n;
        }
        if (lane == 63) s_wsum[wid] = (uint)p2;
        __syncthreads();
        int kbase = p2 - kc;
        for (int w = 0; w < wid; ++w) kbase += (int)s_wsum[w];
        {
            int slot = kbase;
#pragma unroll
            for (int i = 0; i < VPT; ++i) {
                if (vals[i] >= thf) {
                    if (slot < 64) {
                        list_m[r][slot] = (uint)((i << 8) + tid);
                        list_v[r][slot] = vals[i];
                    }
                    slot++;
                }
            }
        }
        __syncthreads();
    };

    select_row(vA, 0);
    select_row(vB, 1);

    // 7. output: threads 0..99 -> row A, threads 128..227 -> row B
    const int grp = tid >> 7;        // 0 or 1
    const int c   = tid & 127;
    if (c < NB_CLASSES) {
        float a0 = b2[c], a1 = 0.0f;
#pragma unroll
        for (int j = 0; j < 64; j += 2) {
            const uint m0 = list_m[grp][j], m1 = list_m[grp][j + 1];
            float w0, w1;
            if (USE_W2T) {
                w0 = w2t[(size_t)m0 * NB_CLASSES + c];
                w1 = w2t[(size_t)m1 * NB_CLASSES + c];
            } else {
                w0 = fmaxf(w2[(size_t)c * MB_DIM + m0], 0.0f);
                w1 = fmaxf(w2[(size_t)c * MB_DIM + m1], 0.0f);
            }
            a0 = fmaf(list_v[grp][j],     w0, a0);
            a1 = fmaf(list_v[grp][j + 1], w1, a1);
        }
        out[(size_t)(brow + grp) * NB_CLASSES + c] = a0 + a1;
    }
}

// ---------------------------------------------------------------------------
extern "C" void kernel_launch(void* const* d_in, const int* in_sizes, int n_in,
                              void* d_out, int out_size, void* d_ws, size_t ws_size,
                              hipStream_t stream) {
    const float* x  = (const float*)d_in[0];
    const float* w1 = (const float*)d_in[1];
    const float* w2 = (const float*)d_in[2];
    const float* b2 = (const float*)d_in[3];
    float* out = (float*)d_out;

    uint4* idx4 = (uint4*)d_ws;                            // 163840 B
    const size_t W2T_OFF = 163840;
    float* w2t = (float*)((char*)d_ws + W2T_OFF);
    const bool use_w2t =
        ws_size >= W2T_OFF + (size_t)MB_DIM * NB_CLASSES * sizeof(float);

    k_extract<<<(MB_DIM * 64) / 256, 256, 0, stream>>>(w1, idx4);
    if (use_w2t) {
        k_w2t<<<(MB_DIM * NB_CLASSES + 255) / 256, 256, 0, stream>>>(w2, w2t);
        k_main<true><<<BATCH / 2, NTHR, 0, stream>>>(x, idx4, w2t, w2, b2, out);
    } else {
        k_main<false><<<BATCH / 2, NTHR, 0, stream>>>(x, idx4, nullptr, w2, b2, out);
    }
}